// Round 2
// baseline (460.841 us; speedup 1.0000x reference)
//
#include <hip/hip_runtime.h>

// Markov chain log-likelihood, single fused kernel:
//   ll_b = log(init[x_{b,0}]) + sum_{t=1}^{len_b-1} log(trans[x_{b,t-1}, x_{b,t}])
//   out  = -logsumexp_b(ll_b)
//
// Inputs (setup_inputs order):
//   d_in[0] seqs   : int32 [B*S]
//   d_in[1] lengths: int32 [B]
//   d_in[2] init   : fp32  [NUM_STATES]
//   d_in[3] trans  : fp32  [NUM_STATES*NUM_STATES]  (400 MB, random gather)
// Output: fp32 scalar.
//
// Strategy: one block handles 1024 transitions of one sequence (2 per thread
// for MLP). Block partial -> device-scope atomicAdd into per-seq accumulator
// in d_ws. Arrival counter picks the last block, whose first wave does the
// 64-way logsumexp and writes the scalar. Cross-XCD visibility: accumulators
// are read back with atomicAdd(ptr, 0.0f) (performed at the device coherence
// point), and a __threadfence() orders partial-atomic before counter-atomic.

#define B_SEQ 64
#define S_LEN 4096
#define NSTATES 10000
#define TPB 256
#define TPT 2                                    // transitions per thread
#define BLOCKS_PER_SEQ (S_LEN / (TPB * TPT))     // 8
#define NBLOCKS (B_SEQ * BLOCKS_PER_SEQ)         // 512

// ws layout (floats): [0..63] per-seq accumulators, [64] arrival counter (int)
#define WS_ZERO_BYTES 512

__global__ __launch_bounds__(TPB) void markov_fused(
    const int* __restrict__ seqs,
    const int* __restrict__ lengths,
    const float* __restrict__ init,
    const float* __restrict__ trans,
    float* __restrict__ ws,
    float* __restrict__ out) {
    const int blk = blockIdx.x;
    const int b   = blk >> 3;          // / BLOCKS_PER_SEQ (8)
    const int p   = blk & 7;           // % BLOCKS_PER_SEQ
    const int tid = threadIdx.x;

    const int len = lengths[b];
    const int* __restrict__ seqb = seqs + b * S_LEN;

    float v = 0.0f;
    #pragma unroll
    for (int k = 0; k < TPT; ++k) {
        const int t = p * (TPB * TPT) + k * TPB + tid + 1;  // target index in [1,S)
        if (t < len) {
            const unsigned s0 = (unsigned)seqb[t - 1];
            const unsigned s1 = (unsigned)seqb[t];
            // s0*10000+s1 < 1e8 < 2^31: 32-bit index math
            v += __logf(trans[s0 * (unsigned)NSTATES + s1]);
        }
    }

    // wave (64-lane) shuffle reduction
    #pragma unroll
    for (int off = 32; off > 0; off >>= 1)
        v += __shfl_down(v, off, 64);

    __shared__ float wsum[TPB / 64];
    __shared__ int last_flag;
    const int wave = tid >> 6;
    const int lane = tid & 63;
    if (lane == 0) wsum[wave] = v;
    __syncthreads();

    if (tid == 0) {
        float total = 0.0f;
        #pragma unroll
        for (int w = 0; w < TPB / 64; ++w) total += wsum[w];
        atomicAdd(&ws[b], total);               // device-scope (coherence point)
        __threadfence();                        // order: partial before counter
        int prev = atomicAdd((int*)&ws[B_SEQ], 1);
        last_flag = (prev == NBLOCKS - 1);
    }
    __syncthreads();
    if (!last_flag) return;

    // ---- last block: finalize with first wave (64 lanes == B_SEQ) ----
    if (tid < B_SEQ) {
        const int bb = tid;
        // atomic read-back: performed at device coherence point, never stale
        float ll = atomicAdd(&ws[bb], 0.0f);
        ll += __logf(init[seqs[bb * S_LEN]]);

        float m = ll;
        #pragma unroll
        for (int off = 32; off > 0; off >>= 1)
            m = fmaxf(m, __shfl_down(m, off, 64));
        m = __shfl(m, 0, 64);

        float e = __expf(ll - m);
        #pragma unroll
        for (int off = 32; off > 0; off >>= 1)
            e += __shfl_down(e, off, 64);

        if (bb == 0) out[0] = -(m + __logf(e));
    }
}

extern "C" void kernel_launch(void* const* d_in, const int* in_sizes, int n_in,
                              void* d_out, int out_size, void* d_ws, size_t ws_size,
                              hipStream_t stream) {
    const int* seqs    = (const int*)d_in[0];
    const int* lengths = (const int*)d_in[1];
    const float* init  = (const float*)d_in[2];
    const float* trans = (const float*)d_in[3];
    float* out         = (float*)d_out;
    float* ws          = (float*)d_ws;

    // zero the accumulators + arrival counter (d_ws is poisoned 0xAA)
    hipMemsetAsync(d_ws, 0, WS_ZERO_BYTES, stream);
    markov_fused<<<NBLOCKS, TPB, 0, stream>>>(seqs, lengths, init, trans, ws, out);
}

// Round 3
// 439.719 us; speedup vs baseline: 1.0480x; 1.0480x over previous
//
#include <hip/hip_runtime.h>

// Markov chain log-likelihood:
//   ll_b = log(init[x_{b,0}]) + sum_{t=1}^{len_b-1} log(trans[x_{b,t-1}, x_{b,t}])
//   out  = -logsumexp_b(ll_b)
//
// Inputs (setup_inputs order):
//   d_in[0] seqs   : int32 [B*S]
//   d_in[1] lengths: int32 [B]
//   d_in[2] init   : fp32  [NUM_STATES]
//   d_in[3] trans  : fp32  [NUM_STATES*NUM_STATES]  (400 MB, random gather)
// Output: fp32 scalar.
//
// R3 = R1 structure (fastest measured: 440 µs vs 461 µs fused/atomics),
// with 32-bit gather indexing. Two kernels, no atomics, no memset node.
// Rationale: measured loop is dominated by harness reset fills (~420 µs);
// kernel side is latency-bound gather, best served by max wave count
// (1 transition/thread -> 4096 waves = 16/CU in flight).

#define B_SEQ 64
#define S_LEN 4096
#define NSTATES 10000
#define P_BLOCKS 16          // partial blocks per sequence
#define BLOCK_T 256          // threads per block (P_BLOCKS*BLOCK_T = S_LEN)

// Kernel 1: per-transition gather + log, block reduction -> ws[b*P + p]
__global__ __launch_bounds__(BLOCK_T) void markov_partials(
    const int* __restrict__ seqs,
    const int* __restrict__ lengths,
    const float* __restrict__ trans,
    float* __restrict__ ws) {
    const int b = blockIdx.y;
    const int p = blockIdx.x;
    const int tid = threadIdx.x;

    const int len = lengths[b];
    const int t = p * BLOCK_T + tid + 1;   // transition target index in [1, S)

    float v = 0.0f;
    if (t < len) {
        const unsigned s0 = (unsigned)seqs[b * S_LEN + t - 1];
        const unsigned s1 = (unsigned)seqs[b * S_LEN + t];
        // s0*10000+s1 < 1e8 < 2^31: 32-bit index math
        v = __logf(trans[s0 * (unsigned)NSTATES + s1]);
    }

    // wave (64-lane) shuffle reduction
    #pragma unroll
    for (int off = 32; off > 0; off >>= 1)
        v += __shfl_down(v, off, 64);

    // cross-wave reduction via LDS (4 waves of 64)
    __shared__ float wsum[BLOCK_T / 64];
    const int wave = tid >> 6;
    const int lane = tid & 63;
    if (lane == 0) wsum[wave] = v;
    __syncthreads();
    if (tid == 0) {
        float total = 0.0f;
        #pragma unroll
        for (int w = 0; w < BLOCK_T / 64; ++w) total += wsum[w];
        ws[b * P_BLOCKS + p] = total;
    }
}

// Kernel 2: one wave. Lane b: ll_b = log(init[x_{b,0}]) + sum of partials,
// then wave logsumexp, lane 0 writes -result.
__global__ __launch_bounds__(64) void markov_finalize(
    const int* __restrict__ seqs,
    const float* __restrict__ init,
    const float* __restrict__ ws,
    float* __restrict__ out) {
    const int b = threadIdx.x;   // 0..63

    float ll = __logf(init[seqs[b * S_LEN]]);
    #pragma unroll
    for (int p = 0; p < P_BLOCKS; ++p)
        ll += ws[b * P_BLOCKS + p];

    // wave max
    float m = ll;
    #pragma unroll
    for (int off = 32; off > 0; off >>= 1)
        m = fmaxf(m, __shfl_down(m, off, 64));
    m = __shfl(m, 0, 64);

    float e = __expf(ll - m);
    #pragma unroll
    for (int off = 32; off > 0; off >>= 1)
        e += __shfl_down(e, off, 64);

    if (b == 0)
        out[0] = -(m + __logf(e));
}

extern "C" void kernel_launch(void* const* d_in, const int* in_sizes, int n_in,
                              void* d_out, int out_size, void* d_ws, size_t ws_size,
                              hipStream_t stream) {
    const int* seqs    = (const int*)d_in[0];
    const int* lengths = (const int*)d_in[1];
    const float* init  = (const float*)d_in[2];
    const float* trans = (const float*)d_in[3];
    float* out         = (float*)d_out;
    float* ws          = (float*)d_ws;   // needs B_SEQ * P_BLOCKS floats = 4 KB

    dim3 grid(P_BLOCKS, B_SEQ);
    markov_partials<<<grid, BLOCK_T, 0, stream>>>(seqs, lengths, trans, ws);
    markov_finalize<<<1, 64, 0, stream>>>(seqs, init, ws, out);
}